// Round 8
// baseline (10273.947 us; speedup 1.0000x reference)
//
#include <hip/hip_runtime.h>
#include <stdint.h>

// SpatialGRU on MI355X, round 10: overlap tail-weight misses + shorten chain.
// r9 post-mortem: steady FETCH = 285KB/block-step == serial-tail weights
// (wp1 kb4-7 + wp2, 335KB) missing L2 every step ON the wavefront chain;
// persistent slot (38us) == multi-launch dispatch (37us) -> floor is the
// phase-serialized per-cell cost (7 full barrier drains), not sync.
// Changes vs r9:
//  (1) waves 14-15 (idle pre-B1) warm-touch the tail weights every step,
//      concurrent with part A (plain cached loads, asm-free DCE keep);
//  (2) combine publishes h DIRECTLY from z-registers (16 dword sc1 stores),
//      vmcnt(0) + LDS atomicAdd; 8th z-wave fires the flag -- B6/B7 leave
//      the chain, barriers 7 -> 6/step;
//  (3) stage-A (hd copy + x cols) done by the 8 non-z waves, parallel with
//      combine; x prefetch restricted to those waves.

typedef __bf16 bf16x8 __attribute__((ext_vector_type(8)));
typedef float  f32x4  __attribute__((ext_vector_type(4)));
typedef unsigned short ushort4v __attribute__((ext_vector_type(4)));
typedef unsigned short ushort2v __attribute__((ext_vector_type(2)));
typedef unsigned int   u32x4    __attribute__((ext_vector_type(4)));

#define QPITCH 424   // 416 q cols + 8 pad (bf16 elems)
#define HPITCH 132   // fp32 h rows padded +4

__device__ int g_progress[160];   // cells completed per block

__device__ __forceinline__ unsigned short f2bf(float x) {
  unsigned int u = __builtin_bit_cast(unsigned int, x);
  u = u + 0x7FFFu + ((u >> 16) & 1u);          // round-to-nearest-even
  return (unsigned short)(u >> 16);
}
__device__ __forceinline__ float bf2f(unsigned short h) {
  unsigned int u = ((unsigned int)h) << 16;
  return __builtin_bit_cast(float, u);
}
__device__ __forceinline__ float sigm(float x) {
  x = fminf(fmaxf(x, -30.f), 30.f);
  return 1.f / (1.f + __expf(-x));
}
__device__ __forceinline__ float tanh_fast(float x) {
  x = fminf(fmaxf(x, -15.f), 15.f);
  float e = __expf(2.f * x);
  return (e - 1.f) / (e + 1.f);
}

// Device-scope (LLC-served) ops for the cross-XCD ring.
__device__ __forceinline__ void llc_load32(const float* p, f32x4& a, f32x4& b) {
  asm volatile("global_load_dwordx4 %0, %2, off sc1\n\t"
               "global_load_dwordx4 %1, %3, off sc1\n\t"
               "s_waitcnt vmcnt(0)"
               : "=&v"(a), "=&v"(b)
               : "v"(p), "v"(p + 4)
               : "memory");
}
__device__ __forceinline__ void llc_store4(float* p, float v) {
  asm volatile("global_store_dword %0, %1, off sc1"
               :: "v"(p), "v"(v) : "memory");
}

// ---------------------------------------------------------------------------
// prep: identical to round 9 (verified).
// ---------------------------------------------------------------------------
__global__ void prep_kernel(const float* __restrict__ Wr, const float* __restrict__ Wz,
                            const float* __restrict__ Wij, const float* __restrict__ WU,
                            const float* __restrict__ br, const float* __restrict__ bz,
                            const float* __restrict__ bij,
                            unsigned short* __restrict__ wp1, unsigned short* __restrict__ wp2,
                            float* __restrict__ bfused) {
  int blk = blockIdx.x, lane = threadIdx.x;
  if (blk < 728) {                       // 13 kb * 56 ntiles for W' (n<896)
    int kb = blk / 56, nt = blk % 56;
    int n = nt * 16 + (lane & 15);
    int kb8 = kb * 32 + (lane >> 4) * 8;
    unsigned short v[8];
#pragma unroll
    for (int j = 0; j < 8; ++j) {
      int k = kb8 + j; float w;
      if (n < 384) w = Wr[n * 416 + k];
      else { int u = (n - 384) >> 2, g = (n - 384) & 3; w = Wz[(g * 128 + u) * 416 + k]; }
      v[j] = f2bf(w);
    }
    ushort4v* dst = (ushort4v*)(wp1 + ((size_t)(kb * 56 + nt) * 64 + lane) * 8);
    dst[0] = (ushort4v){v[0], v[1], v[2], v[3]};
    dst[1] = (ushort4v){v[4], v[5], v[6], v[7]};
  } else if (blk < 728 + 104) {          // 13 kb * 8 ntiles for [WU' | Wij]
    int b2 = blk - 728;
    int kb = b2 >> 3, nt = b2 & 7;
    int f = lane & 15;
    int u = nt * 16 + ((f & 3) * 4) + (f >> 2);   // row permutation
    int kb8 = kb * 32 + (lane >> 4) * 8;
    unsigned short v[8];
#pragma unroll
    for (int j = 0; j < 8; ++j) {
      int c = kb8 + j; float w;
      if (c < 384) {
        int s = (c < 128) ? c + 128 : (c < 256 ? c - 128 : c);  // hl,ht,hd -> ht,hl,hd
        w = WU[u * 384 + s];
      } else {
        w = Wij[u * 32 + (c - 384)];
      }
      v[j] = f2bf(w);
    }
    ushort4v* dst = (ushort4v*)(wp2 + ((size_t)(kb * 8 + nt) * 64 + lane) * 8);
    dst[0] = (ushort4v){v[0], v[1], v[2], v[3]};
    dst[1] = (ushort4v){v[4], v[5], v[6], v[7]};
  } else if (blk == 832) {               // fused bias (1024 fp32)
#pragma unroll
    for (int i = 0; i < 16; ++i) {
      int n = lane * 16 + i; float v;
      if (n < 384) v = br[n];
      else if (n < 896) { int u = (n - 384) >> 2, g = (n - 384) & 3; v = bz[g * 128 + u]; }
      else v = bij[n - 896];
      bfused[n] = v;
    }
  } else {                               // zero progress flags
    for (int i = lane; i < 160; i += 64)
      __hip_atomic_store(&g_progress[i], 0, __ATOMIC_RELAXED, __HIP_MEMORY_SCOPE_AGENT);
  }
}

// one GEMM1 K-step (16 MFMA over the wave's 64n x 64b tile)
#define G1_STEP(KB)                                                                        \
  {                                                                                        \
    bf16x8 wf[4], qf[4];                                                                   \
    _Pragma("unroll")                                                                      \
    for (int mt = 0; mt < 4; ++mt)                                                         \
      wf[mt] = *(const bf16x8*)(wp1 + ((size_t)((KB) * 56 + ntb + mt) * 64 + lane) * 8);   \
    _Pragma("unroll")                                                                      \
    for (int bt = 0; bt < 4; ++bt)                                                         \
      qf[bt] = *(const bf16x8*)(lds + (size_t)(bt * 16 + l15) * QPITCH + (KB) * 32 + quad * 8); \
    _Pragma("unroll")                                                                      \
    for (int mt = 0; mt < 4; ++mt)                                                         \
      _Pragma("unroll")                                                                    \
      for (int bt = 0; bt < 4; ++bt)                                                       \
        acc[mt][bt] = __builtin_amdgcn_mfma_f32_16x16x32_bf16(wf[mt], qf[bt], acc[mt][bt], 0, 0, 0); \
  }

// ---------------------------------------------------------------------------
// Persistent wavefront kernel. LDS (155,648 B):
//   q bf16 [64][QPITCH]     @ 0       cols: ht(0..127)|hl(128..255)|hd|x
//     (q row-0 pad bytes 832..839 reused: counter @832, DCE sink @836)
//   htopF fp32 [64][HPITCH] @ 54,272  own h(l-1) for the z-fold
//   hlD0/hlD1 fp32          @ 88,064 / 121,856   h_left double buffer
// ---------------------------------------------------------------------------
__global__ __launch_bounds__(1024)
void gru_persist(const float* __restrict__ x, const float* __restrict__ bfused,
                 const unsigned short* __restrict__ wp1, const unsigned short* __restrict__ wp2,
                 float* __restrict__ ring,
                 unsigned short* __restrict__ xp,   // nullable: per-block [80][2048] bf16
                 float* __restrict__ out) {
  const int blk = blockIdx.x;
  const int rc = (blk < 80) ? blk : blk - 80;
  const int bh = (blk < 80) ? 0 : 1;
  const int tid = threadIdx.x;
  const int wave = tid >> 6, lane = tid & 63;
  const int quad = lane >> 4, l15 = lane & 15;
  const int i2 = tid * 2;                        // init-time (b_local, c) pair id
  const int bb = i2 >> 5, cc = i2 & 31;

  extern __shared__ char smem[];
  unsigned short* lds = (unsigned short*)smem;
  float* htopF = (float*)(smem + 54272);
  float* hlD0  = (float*)(smem + 88064);
  float* hlD1  = (float*)(smem + 121856);
  unsigned int* cnt  = (unsigned int*)(smem + 832);   // q row-0 pad
  volatile unsigned int* sink = (volatile unsigned int*)(smem + 836);

  float* ringMine = ring + (size_t)blk * 24576;  // 3 slots x 8192 fp32
  unsigned short* xpB = xp ? (xp + (size_t)blk * 163840) : nullptr;

  // stage-A wave set: r-waves 0..5 + waves 14,15 (z-waves excluded)
  const bool stgA = (wave < 6) || (wave >= 14);
  const int sid = ((wave < 6) ? wave : wave - 8) * 64 + lane;   // 0..511

  // ---- init: zero h buffers + q cols 0..383; counter ----
  for (int i = tid; i < 64 * HPITCH; i += 1024) { htopF[i] = 0.f; hlD0[i] = 0.f; hlD1[i] = 0.f; }
  {
    int r = tid >> 4, c0 = (tid & 15) * 24;      // 64 rows x 384 cols
#pragma unroll
    for (int j = 0; j < 6; ++j)
      *(ushort4v*)(lds + (size_t)r * QPITCH + c0 + j * 4) = (ushort4v){0, 0, 0, 0};
  }
  if (tid == 0) { *cnt = 0u; *sink = 0u; }
  // ---- x: one-time private transpose into xp (cached gathers: 32 blocks
  // share each 128B line -> LLC/L2 dedup; r9-verified) ----
  if (xpB) {
    const float* xb = x + (size_t)(bh * 2048 + i2) * 6400 + rc;
#pragma unroll 4
    for (int l = 0; l < 80; ++l) {
      float v0 = xb[l * 80];
      float v1 = xb[6400 + l * 80];
      ushort2v o = (ushort2v){f2bf(v0), f2bf(v1)};
      __builtin_nontemporal_store(__builtin_bit_cast(unsigned int, o),
                                  (unsigned int*)(xpB + (size_t)l * 2048 + i2));
      if (l == 0)
        *(ushort2v*)(lds + (size_t)bb * QPITCH + 384 + cc) = o;
    }
  } else {
    const float* xb = x + rc;
    float v0 = xb[(size_t)(bh * 2048 + i2) * 6400];
    float v1 = xb[(size_t)(bh * 2048 + i2 + 1) * 6400];
    *(ushort2v*)(lds + (size_t)bb * QPITCH + 384 + cc) = (ushort2v){f2bf(v0), f2bf(v1)};
  }
  __syncthreads();

  const int ntb = wave * 4;                      // GEMM1 n-tile base (waves 0..13)
  const int jz = wave - 6;                       // z-wave id 0..7 (waves 6..13)
  const bool isOut = (rc == 79);                 // block-uniform

  f32x4 biasv[4];
#pragma unroll
  for (int mt = 0; mt < 4; ++mt)
    biasv[mt] = *(const f32x4*)(bfused + ((wave < 14 ? wave : 0) * 64) + mt * 16 + quad * 4);
  float bij_r[4];
#pragma unroll
  for (int mt = 0; mt < 4; ++mt)
    bij_r[mt] = (wave >= 6 && wave < 14) ? bfused[896 + 16 * jz + 4 * mt + quad] : 0.f;

  float hz_r[4][4], zi_r[4][4];                  // z-wave state across phases

  for (int l = 0; l < 80; ++l) {
    // ---- x prefetch for l+1 (stage-A waves only; 8B nt per thread) ----
    ushort4v xn4 = (ushort4v){0, 0, 0, 0};
    if (l < 79 && stgA) {
      if (xpB) {
        unsigned long long t = __builtin_nontemporal_load(
            (const unsigned long long*)(xpB + (size_t)(l + 1) * 2048 + sid * 4));
        xn4 = __builtin_bit_cast(ushort4v, t);
      } else {
        const float* xb = x + (size_t)(l + 1) * 80 + rc;
#pragma unroll
        for (int j = 0; j < 4; ++j)
          xn4[j] = f2bf(xb[(size_t)(bh * 2048 + sid * 4 + j) * 6400]);
      }
    }

    // ---- part A (waves 0..13): kb {0..3, 8..12} — neighbor-free ----
    // ---- waves 14,15: warm-touch tail weights (wp1 kb4..7 + wp2) into L2 ----
    f32x4 acc[4][4];
    if (wave < 14) {
#pragma unroll
      for (int mt = 0; mt < 4; ++mt)
#pragma unroll
        for (int bt = 0; bt < 4; ++bt) acc[mt][bt] = (f32x4){0.f, 0.f, 0.f, 0.f};
#pragma unroll
      for (int t = 0; t < 9; ++t) {
        const int kb = (t < 4) ? t : t + 4;
        G1_STEP(kb)
      }
    } else {
      // 335KB: wp1 kb4..7 = 14336 u32x4, wp2 = 6656 u32x4. Cached loads fill
      // L2 under part A + spin; part B / GEMM2 then L2-hit. DCE-kept via an
      // impossible-value store into the q pad (cannot be proven dead).
      const int lid = (wave - 14) * 64 + lane;   // 0..127
      unsigned int s = 0;
      const u32x4* p1 = (const u32x4*)(wp1 + (size_t)4 * 56 * 64 * 8);
      for (int i = lid; i < 14336; i += 128) { u32x4 v = p1[i]; s += v[0]; }
      const u32x4* p2 = (const u32x4*)wp2;
      for (int i = lid; i < 6656; i += 128) { u32x4 v = p2[i]; s += v[0]; }
      if (s == 0x9E3779B9u) *sink = s;
    }

    // ---- spin (single lane, BOUNDED): left done row l; right freed slot ----
    if (tid == 0) {
      if (rc > 0) {
        int guard = 0;
        while (__hip_atomic_load(&g_progress[blk - 1], __ATOMIC_RELAXED, __HIP_MEMORY_SCOPE_AGENT) < l + 1
               && guard < 400000) { __builtin_amdgcn_s_sleep(1); ++guard; }
      }
      if (rc < 79) {
        int guard = 0;
        while (__hip_atomic_load(&g_progress[blk + 1], __ATOMIC_RELAXED, __HIP_MEMORY_SCOPE_AGENT) < l - 2
               && guard < 400000) { __builtin_amdgcn_s_sleep(1); ++guard; }
      }
    }
    asm volatile("" ::: "memory");
    __syncthreads();                                             // B1

    // ---- stage B: h_left from neighbor ring (device-scope dwordx4) ----
    if (rc > 0) {
      const float* src = ring + (size_t)(blk - 1) * 24576 + (size_t)(l % 3) * 8192 + tid * 8;
      f32x4 a, b;
      llc_load32(src, a, b);
      int bl = (tid * 8) >> 7, u = (tid * 8) & 127;
      float* hlF = (l & 1) ? hlD1 : hlD0;
      *(f32x4*)(hlF + bl * HPITCH + u)     = a;
      *(f32x4*)(hlF + bl * HPITCH + u + 4) = b;
      *(ushort4v*)(lds + (size_t)bl * QPITCH + 128 + u)     = (ushort4v){f2bf(a[0]), f2bf(a[1]), f2bf(a[2]), f2bf(a[3])};
      *(ushort4v*)(lds + (size_t)bl * QPITCH + 128 + u + 4) = (ushort4v){f2bf(b[0]), f2bf(b[1]), f2bf(b[2]), f2bf(b[3])};
    }
    __syncthreads();                                             // B2

    // ---- part B: kb 4..7 (hl) — weights pre-warmed into L2 ----
    if (wave < 14) {
#pragma unroll
      for (int kb = 4; kb < 8; ++kb) { G1_STEP(kb) }
    }
    __syncthreads();                                             // B3

    // ---- elementwise ----
    if (wave < 6) {
      // r class: sigmoid, A2' = r*q in place (shift maps r col -> q col)
      const int rn0 = wave * 64;
      const int shift = (rn0 < 128) ? 128 : (rn0 < 256 ? -128 : 0);
#pragma unroll
      for (int mt = 0; mt < 4; ++mt)
#pragma unroll
        for (int bt = 0; bt < 4; ++bt) {
          int n0 = rn0 + mt * 16 + quad * 4;
          int row = bt * 16 + l15;
          unsigned short* p = lds + (size_t)row * QPITCH + n0 + shift;
          ushort4v qv = *(ushort4v*)p;
          ushort4v o;
#pragma unroll
          for (int g = 0; g < 4; ++g) {
            float r = sigm(acc[mt][bt][g] + biasv[mt][g]);
            o[g] = f2bf(bf2f(qv[g]) * r);
          }
          *(ushort4v*)p = o;
        }
    } else if (wave < 14) {
      // z class: lane-local softmax; fold fp32 h's; keep hz/zi in registers
      const float* hlF = (l & 1) ? hlD1 : hlD0;
      const float* hdF = (l & 1) ? hlD0 : hlD1;
#pragma unroll
      for (int mt = 0; mt < 4; ++mt)
#pragma unroll
        for (int bt = 0; bt < 4; ++bt) {
          int u = 16 * jz + 4 * mt + quad;
          int bl = 16 * bt + l15;
          float v0 = acc[mt][bt][0] + biasv[mt][0];
          float v1 = acc[mt][bt][1] + biasv[mt][1];
          float v2 = acc[mt][bt][2] + biasv[mt][2];
          float v3 = acc[mt][bt][3] + biasv[mt][3];
          float m = fmaxf(fmaxf(v0, v1), fmaxf(v2, v3));
          float e0 = __expf(v0 - m), e1 = __expf(v1 - m);
          float e2 = __expf(v2 - m), e3 = __expf(v3 - m);
          float inv = 1.f / (e0 + e1 + e2 + e3);
          float hl = hlF[bl * HPITCH + u];
          float ht = htopF[bl * HPITCH + u];
          float hd = hdF[bl * HPITCH + u];
          hz_r[mt][bt] = (e1 * hl + e2 * ht + e3 * hd) * inv;  // zl,zt,zd fold
          zi_r[mt][bt] = e0 * inv;
        }
    }
    __syncthreads();                                             // B4

    // ---- GEMM2 (z-waves only): hU+cw over K=416 incl. Wij block ----
    f32x4 acc2[4];
    if (wave >= 6 && wave < 14) {
#pragma unroll
      for (int bt = 0; bt < 4; ++bt) acc2[bt] = (f32x4){0.f, 0.f, 0.f, 0.f};
#pragma unroll
      for (int kb = 0; kb < 13; ++kb) {
        bf16x8 wf = *(const bf16x8*)(wp2 + ((size_t)(kb * 8 + jz) * 64 + lane) * 8);
#pragma unroll
        for (int bt = 0; bt < 4; ++bt) {
          bf16x8 qf = *(const bf16x8*)(lds + (size_t)(bt * 16 + l15) * QPITCH + kb * 32 + quad * 8);
          acc2[bt] = __builtin_amdgcn_mfma_f32_16x16x32_bf16(wf, qf, acc2[bt], 0, 0, 0);
        }
      }
    }
    __syncthreads();                                             // B5

    // ---- combine + DIRECT publish (z) ∥ stage-A (r-waves + 14,15) ----
    if (wave >= 6 && wave < 14) {
      float* slot = ringMine + (size_t)(l % 3) * 8192;
#pragma unroll
      for (int mt = 0; mt < 4; ++mt)
#pragma unroll
        for (int bt = 0; bt < 4; ++bt) {
          float h = hz_r[mt][bt] + zi_r[mt][bt] * tanh_fast(acc2[bt][mt] + bij_r[mt]);
          int bl = 16 * bt + l15;
          int uu = 16 * jz + 4 * mt + quad;
          llc_store4(slot + bl * 128 + uu, h);           // ring, device scope
          if (isOut && l == 79) out[(size_t)(bh * 8192) + bl * 128 + uu] = h;
          htopF[bl * HPITCH + uu] = h;                   // fp32 ht for l+1 z-fold
          lds[(size_t)bl * QPITCH + uu] = f2bf(h);       // bf16 ht col for l+1
        }
      asm volatile("s_waitcnt vmcnt(0)" ::: "memory");   // ring stores complete
      if (lane == 0) {
        unsigned int old = atomicAdd(cnt, 1u);           // LDS, returns old
        if (old == 8u * (unsigned)l + 7u)                // 8th z-wave fires flag
          __hip_atomic_store(&g_progress[blk], l + 1, __ATOMIC_RELAXED, __HIP_MEMORY_SCOPE_AGENT);
      }
    } else if (l < 79) {
      // stage A: hd (q cols 256..383) <- this step's hl fp32; x from prefetch
      const float* hdF = (l & 1) ? hlD1 : hlD0;          // = hlF(l)
      int idx = sid * 16, bl = idx >> 7, u = idx & 127;
#pragma unroll
      for (int j = 0; j < 4; ++j) {
        f32x4 a = *(const f32x4*)(hdF + bl * HPITCH + u + 4 * j);
        *(ushort4v*)(lds + (size_t)bl * QPITCH + 256 + u + 4 * j) =
            (ushort4v){f2bf(a[0]), f2bf(a[1]), f2bf(a[2]), f2bf(a[3])};
      }
      int row = (sid * 4) >> 5, c4 = (sid * 4) & 31;
      *(ushort4v*)(lds + (size_t)row * QPITCH + 384 + c4) = xn4;
    }
    __syncthreads();                                             // B6 (LDS q/htopF ready)
  }
}

// ---------------------------------------------------------------------------
extern "C" void kernel_launch(void* const* d_in, const int* in_sizes, int n_in,
                              void* d_out, int out_size, void* d_ws, size_t ws_size,
                              hipStream_t stream) {
  const float* x   = (const float*)d_in[0];
  const float* Wr  = (const float*)d_in[1];
  const float* br  = (const float*)d_in[2];
  const float* Wz  = (const float*)d_in[3];
  const float* bz  = (const float*)d_in[4];
  const float* Wij = (const float*)d_in[5];
  const float* bij = (const float*)d_in[6];
  const float* WU  = (const float*)d_in[7];
  float* out = (float*)d_out;

  // ws layout: wp1 | wp2 | bfused | ring | xp
  char* ws = (char*)d_ws;
  unsigned short* wp1 = (unsigned short*)(ws);                 //    745,472 B
  unsigned short* wp2 = (unsigned short*)(ws + 745472);        //    106,496 B
  float* bfused       = (float*)(ws + 851968);                 //      4,096 B
  float* ring         = (float*)(ws + 856064);                 // 15,728,640 B
  // xp: 160 blocks x 80 l x 2048 bf16 = 52,428,800 B (only if ws allows)
  unsigned short* xp  = (ws_size >= 69013504ull)
                        ? (unsigned short*)(ws + 16584704) : nullptr;

  (void)hipFuncSetAttribute((const void*)gru_persist,
                            hipFuncAttributeMaxDynamicSharedMemorySize, 155648);

  prep_kernel<<<834, 64, 0, stream>>>(Wr, Wz, Wij, WU, br, bz, bij, wp1, wp2, bfused);
  gru_persist<<<160, 1024, 155648, stream>>>(x, bfused, wp1, wp2, ring, xp, out);
}

// Round 9
// 7575.642 us; speedup vs baseline: 1.3562x; 1.3562x over previous
//
#include <hip/hip_runtime.h>
#include <stdint.h>

// SpatialGRU on MI355X, round 11: r9 base (6213us, best pass) + ONE change:
// waves 14-15 warm-touch the serial-tail weights (wp1 kb4..7 + wp2, 335KB)
// into L2 every step, concurrent with part A + spin.
// r10 post-mortem: its 65% regression was the de-coalesced z-register publish
// (8192 scattered scalar sc1 stores/block-step on the chain + vmcnt(0) before
// the flag) -- reverted wholesale; publish stays the coalesced LDS relay.
// Warm-touch was bundled in r10 and never attributed; this round isolates it.
// Theory: steady FETCH ~185KB/block-step == tail weights missing L2 inside
// the serial tail (stage-B -> partB -> GEMM2), ~900cy each, ~15-20us of the
// 38us slot. Warm-touch moves those fills under part A where they overlap.

typedef __bf16 bf16x8 __attribute__((ext_vector_type(8)));
typedef float  f32x4  __attribute__((ext_vector_type(4)));
typedef unsigned short ushort4v __attribute__((ext_vector_type(4)));
typedef unsigned short ushort2v __attribute__((ext_vector_type(2)));
typedef unsigned int   u32x4    __attribute__((ext_vector_type(4)));

#define QPITCH 424   // 416 q cols + 8 pad (bf16 elems)
#define HPITCH 132   // fp32 h rows padded +4

__device__ int g_progress[160];   // cells completed per block

__device__ __forceinline__ unsigned short f2bf(float x) {
  unsigned int u = __builtin_bit_cast(unsigned int, x);
  u = u + 0x7FFFu + ((u >> 16) & 1u);          // round-to-nearest-even
  return (unsigned short)(u >> 16);
}
__device__ __forceinline__ float bf2f(unsigned short h) {
  unsigned int u = ((unsigned int)h) << 16;
  return __builtin_bit_cast(float, u);
}
__device__ __forceinline__ float sigm(float x) {
  x = fminf(fmaxf(x, -30.f), 30.f);
  return 1.f / (1.f + __expf(-x));
}
__device__ __forceinline__ float tanh_fast(float x) {
  x = fminf(fmaxf(x, -15.f), 15.f);
  float e = __expf(2.f * x);
  return (e - 1.f) / (e + 1.f);
}

// Device-scope (LLC-served) ops for the cross-XCD ring.
__device__ __forceinline__ void llc_load32(const float* p, f32x4& a, f32x4& b) {
  asm volatile("global_load_dwordx4 %0, %2, off sc1\n\t"
               "global_load_dwordx4 %1, %3, off sc1\n\t"
               "s_waitcnt vmcnt(0)"
               : "=&v"(a), "=&v"(b)
               : "v"(p), "v"(p + 4)
               : "memory");
}
__device__ __forceinline__ void llc_store16(float* p, f32x4 v) {
  asm volatile("global_store_dwordx4 %0, %1, off sc1"
               :: "v"(p), "v"(v) : "memory");
}

// ---------------------------------------------------------------------------
// prep: identical to rounds 9/10 (verified).
// ---------------------------------------------------------------------------
__global__ void prep_kernel(const float* __restrict__ Wr, const float* __restrict__ Wz,
                            const float* __restrict__ Wij, const float* __restrict__ WU,
                            const float* __restrict__ br, const float* __restrict__ bz,
                            const float* __restrict__ bij,
                            unsigned short* __restrict__ wp1, unsigned short* __restrict__ wp2,
                            float* __restrict__ bfused) {
  int blk = blockIdx.x, lane = threadIdx.x;
  if (blk < 728) {                       // 13 kb * 56 ntiles for W' (n<896)
    int kb = blk / 56, nt = blk % 56;
    int n = nt * 16 + (lane & 15);
    int kb8 = kb * 32 + (lane >> 4) * 8;
    unsigned short v[8];
#pragma unroll
    for (int j = 0; j < 8; ++j) {
      int k = kb8 + j; float w;
      if (n < 384) w = Wr[n * 416 + k];
      else { int u = (n - 384) >> 2, g = (n - 384) & 3; w = Wz[(g * 128 + u) * 416 + k]; }
      v[j] = f2bf(w);
    }
    ushort4v* dst = (ushort4v*)(wp1 + ((size_t)(kb * 56 + nt) * 64 + lane) * 8);
    dst[0] = (ushort4v){v[0], v[1], v[2], v[3]};
    dst[1] = (ushort4v){v[4], v[5], v[6], v[7]};
  } else if (blk < 728 + 104) {          // 13 kb * 8 ntiles for [WU' | Wij]
    int b2 = blk - 728;
    int kb = b2 >> 3, nt = b2 & 7;
    int f = lane & 15;
    int u = nt * 16 + ((f & 3) * 4) + (f >> 2);   // row permutation
    int kb8 = kb * 32 + (lane >> 4) * 8;
    unsigned short v[8];
#pragma unroll
    for (int j = 0; j < 8; ++j) {
      int c = kb8 + j; float w;
      if (c < 384) {
        int s = (c < 128) ? c + 128 : (c < 256 ? c - 128 : c);  // hl,ht,hd -> ht,hl,hd
        w = WU[u * 384 + s];
      } else {
        w = Wij[u * 32 + (c - 384)];
      }
      v[j] = f2bf(w);
    }
    ushort4v* dst = (ushort4v*)(wp2 + ((size_t)(kb * 8 + nt) * 64 + lane) * 8);
    dst[0] = (ushort4v){v[0], v[1], v[2], v[3]};
    dst[1] = (ushort4v){v[4], v[5], v[6], v[7]};
  } else if (blk == 832) {               // fused bias (1024 fp32)
#pragma unroll
    for (int i = 0; i < 16; ++i) {
      int n = lane * 16 + i; float v;
      if (n < 384) v = br[n];
      else if (n < 896) { int u = (n - 384) >> 2, g = (n - 384) & 3; v = bz[g * 128 + u]; }
      else v = bij[n - 896];
      bfused[n] = v;
    }
  } else {                               // zero progress flags
    for (int i = lane; i < 160; i += 64)
      __hip_atomic_store(&g_progress[i], 0, __ATOMIC_RELAXED, __HIP_MEMORY_SCOPE_AGENT);
  }
}

// one GEMM1 K-step (16 MFMA over the wave's 64n x 64b tile), weights from L2
#define G1_STEP(KB)                                                                        \
  {                                                                                        \
    bf16x8 wf[4], qf[4];                                                                   \
    _Pragma("unroll")                                                                      \
    for (int mt = 0; mt < 4; ++mt)                                                         \
      wf[mt] = *(const bf16x8*)(wp1 + ((size_t)((KB) * 56 + ntb + mt) * 64 + lane) * 8);   \
    _Pragma("unroll")                                                                      \
    for (int bt = 0; bt < 4; ++bt)                                                         \
      qf[bt] = *(const bf16x8*)(lds + (size_t)(bt * 16 + l15) * QPITCH + (KB) * 32 + quad * 8); \
    _Pragma("unroll")                                                                      \
    for (int mt = 0; mt < 4; ++mt)                                                         \
      _Pragma("unroll")                                                                    \
      for (int bt = 0; bt < 4; ++bt)                                                       \
        acc[mt][bt] = __builtin_amdgcn_mfma_f32_16x16x32_bf16(wf[mt], qf[bt], acc[mt][bt], 0, 0, 0); \
  }

// ---------------------------------------------------------------------------
// Persistent wavefront kernel. LDS (155,648 B):
//   q bf16 [64][QPITCH]     @ 0       cols: ht(0..127)|hl(128..255)|hd|x
//     (q row-0 pad bytes 832..835 reused as warm-touch DCE sink)
//   htopF fp32 [64][HPITCH] @ 54,272  own h(l-1), relay source for ring
//   hlD0/hlD1 fp32          @ 88,064 / 121,856   h_left double buffer
// ---------------------------------------------------------------------------
__global__ __launch_bounds__(1024)
void gru_persist(const float* __restrict__ x, const float* __restrict__ bfused,
                 const unsigned short* __restrict__ wp1, const unsigned short* __restrict__ wp2,
                 float* __restrict__ ring,
                 unsigned short* __restrict__ xp,   // nullable: per-block [80][2048] bf16
                 float* __restrict__ out) {
  const int blk = blockIdx.x;
  const int rc = (blk < 80) ? blk : blk - 80;
  const int bh = (blk < 80) ? 0 : 1;
  const int tid = threadIdx.x;
  const int wave = tid >> 6, lane = tid & 63;
  const int quad = lane >> 4, l15 = lane & 15;
  const int i2 = tid * 2;                        // (b_local, c) pair id
  const int bb = i2 >> 5, cc = i2 & 31;

  extern __shared__ char smem[];
  unsigned short* lds = (unsigned short*)smem;
  float* htopF = (float*)(smem + 54272);
  float* hlD0  = (float*)(smem + 88064);
  float* hlD1  = (float*)(smem + 121856);
  volatile unsigned int* sink = (volatile unsigned int*)(smem + 832);  // q row-0 pad

  float* ringMine = ring + (size_t)blk * 24576;  // 3 slots x 8192 fp32
  unsigned short* xpB = xp ? (xp + (size_t)blk * 163840) : nullptr;

  // ---- init: zero h buffers + q cols 0..383 ----
  for (int i = tid; i < 64 * HPITCH; i += 1024) { htopF[i] = 0.f; hlD0[i] = 0.f; hlD1[i] = 0.f; }
  {
    int r = tid >> 4, c0 = (tid & 15) * 24;      // 64 rows x 384 cols
#pragma unroll
    for (int j = 0; j < 6; ++j)
      *(ushort4v*)(lds + (size_t)r * QPITCH + c0 + j * 4) = (ushort4v){0, 0, 0, 0};
  }
  if (tid == 0) *sink = 0u;
  // ---- x: one-time private transpose into xp (cached gathers: 32 blocks
  // share each 128B line -> LLC/L2 dedup; verified r9: FETCH -0.7GB) ----
  if (xpB) {
    const float* xb = x + (size_t)(bh * 2048 + i2) * 6400 + rc;
#pragma unroll 4
    for (int l = 0; l < 80; ++l) {
      float v0 = xb[l * 80];
      float v1 = xb[6400 + l * 80];
      ushort2v o = (ushort2v){f2bf(v0), f2bf(v1)};
      __builtin_nontemporal_store(__builtin_bit_cast(unsigned int, o),
                                  (unsigned int*)(xpB + (size_t)l * 2048 + i2));
      if (l == 0)
        *(ushort2v*)(lds + (size_t)bb * QPITCH + 384 + cc) = o;
    }
  } else {
    const float* xb = x + rc;
    float v0 = xb[(size_t)(bh * 2048 + i2) * 6400];
    float v1 = xb[(size_t)(bh * 2048 + i2 + 1) * 6400];
    *(ushort2v*)(lds + (size_t)bb * QPITCH + 384 + cc) = (ushort2v){f2bf(v0), f2bf(v1)};
  }
  __syncthreads();

  const int ntb = wave * 4;                      // GEMM1 n-tile base (waves 0..13)
  const int jz = wave - 6;                       // z-wave id 0..7 (waves 6..13)
  const bool isOut = (rc == 79);                 // block-uniform

  f32x4 biasv[4];
#pragma unroll
  for (int mt = 0; mt < 4; ++mt)
    biasv[mt] = *(const f32x4*)(bfused + ((wave < 14 ? wave : 0) * 64) + mt * 16 + quad * 4);
  float bij_r[4];
#pragma unroll
  for (int mt = 0; mt < 4; ++mt)
    bij_r[mt] = (wave >= 6 && wave < 14) ? bfused[896 + 16 * jz + 4 * mt + quad] : 0.f;

  float hz_r[4][4], zi_r[4][4];                  // z-wave state across phases

  for (int l = 0; l < 80; ++l) {
    // ---- x prefetch for l+1 (nt; private, read-once; hidden under part A) ----
    unsigned int xn = 0;
    if (l < 79) {
      if (xpB) {
        xn = __builtin_nontemporal_load((const unsigned int*)(xpB + (size_t)(l + 1) * 2048 + i2));
      } else {
        const float* xb = x + (size_t)(l + 1) * 80 + rc;
        float v0 = xb[(size_t)(bh * 2048 + i2) * 6400];
        float v1 = xb[(size_t)(bh * 2048 + i2 + 1) * 6400];
        xn = __builtin_bit_cast(unsigned int, (ushort2v){f2bf(v0), f2bf(v1)});
      }
    }

    // ---- part A (waves 0..13): kb {0..3, 8..12} — neighbor-free ----
    // ---- waves 14,15 (idle until B1): warm-touch tail weights into L2 ----
    f32x4 acc[4][4];
    if (wave < 14) {
#pragma unroll
      for (int mt = 0; mt < 4; ++mt)
#pragma unroll
        for (int bt = 0; bt < 4; ++bt) acc[mt][bt] = (f32x4){0.f, 0.f, 0.f, 0.f};
#pragma unroll
      for (int t = 0; t < 9; ++t) {
        const int kb = (t < 4) ? t : t + 4;
        G1_STEP(kb)
      }
    } else {
      // Tail-weight region: wp1 kb4..7 = 229,376 B (14336 u32x4) + wp2 =
      // 106,496 B (6656 u32x4). Plain cached loads fill L2 under part A +
      // spin; part B / GEMM2 then L2-hit instead of serial LLC misses.
      // DCE-kept via impossible-value conditional store (rule 17).
      const int lid = (wave - 14) * 64 + lane;   // 0..127
      unsigned int s = 0;
      const u32x4* p1 = (const u32x4*)(wp1 + (size_t)4 * 56 * 64 * 8);
      for (int i = lid; i < 14336; i += 128) { u32x4 v = p1[i]; s += v[0]; }
      const u32x4* p2 = (const u32x4*)wp2;
      for (int i = lid; i < 6656; i += 128) { u32x4 v = p2[i]; s += v[0]; }
      if (s == 0x9E3779B9u) *sink = s;
    }

    // ---- spin (single lane, BOUNDED ~12ms/wait): left done row l;
    //      right freed slot. Guard keeps any wedge terminating. ----
    if (tid == 0) {
      if (rc > 0) {
        int guard = 0;
        while (__hip_atomic_load(&g_progress[blk - 1], __ATOMIC_RELAXED, __HIP_MEMORY_SCOPE_AGENT) < l + 1
               && guard < 200000) { __builtin_amdgcn_s_sleep(2); ++guard; }
      }
      if (rc < 79) {
        int guard = 0;
        while (__hip_atomic_load(&g_progress[blk + 1], __ATOMIC_RELAXED, __HIP_MEMORY_SCOPE_AGENT) < l - 2
               && guard < 200000) { __builtin_amdgcn_s_sleep(2); ++guard; }
      }
    }
    asm volatile("" ::: "memory");
    __syncthreads();                                             // B1

    // ---- stage B: h_left from neighbor ring (device-scope dwordx4) ----
    if (rc > 0) {
      const float* src = ring + (size_t)(blk - 1) * 24576 + (size_t)(l % 3) * 8192 + tid * 8;
      f32x4 a, b;
      llc_load32(src, a, b);
      int bl = (tid * 8) >> 7, u = (tid * 8) & 127;
      float* hlF = (l & 1) ? hlD1 : hlD0;
      *(f32x4*)(hlF + bl * HPITCH + u)     = a;
      *(f32x4*)(hlF + bl * HPITCH + u + 4) = b;
      *(ushort4v*)(lds + (size_t)bl * QPITCH + 128 + u)     = (ushort4v){f2bf(a[0]), f2bf(a[1]), f2bf(a[2]), f2bf(a[3])};
      *(ushort4v*)(lds + (size_t)bl * QPITCH + 128 + u + 4) = (ushort4v){f2bf(b[0]), f2bf(b[1]), f2bf(b[2]), f2bf(b[3])};
    }
    __syncthreads();                                             // B2

    // ---- part B: kb 4..7 (hl) — weights pre-warmed into L2 ----
    if (wave < 14) {
#pragma unroll
      for (int kb = 4; kb < 8; ++kb) { G1_STEP(kb) }
    }
    __syncthreads();                                             // B3

    // ---- elementwise ----
    if (wave < 6) {
      // r class: sigmoid, A2' = r*q in place (shift maps r col -> q col)
      const int rn0 = wave * 64;
      const int shift = (rn0 < 128) ? 128 : (rn0 < 256 ? -128 : 0);
#pragma unroll
      for (int mt = 0; mt < 4; ++mt)
#pragma unroll
        for (int bt = 0; bt < 4; ++bt) {
          int n0 = rn0 + mt * 16 + quad * 4;
          int row = bt * 16 + l15;
          unsigned short* p = lds + (size_t)row * QPITCH + n0 + shift;
          ushort4v qv = *(ushort4v*)p;
          ushort4v o;
#pragma unroll
          for (int g = 0; g < 4; ++g) {
            float r = sigm(acc[mt][bt][g] + biasv[mt][g]);
            o[g] = f2bf(bf2f(qv[g]) * r);
          }
          *(ushort4v*)p = o;
        }
    } else if (wave < 14) {
      // z class: lane-local softmax; fold fp32 h's; keep hz/zi in registers
      const float* hlF = (l & 1) ? hlD1 : hlD0;
      const float* hdF = (l & 1) ? hlD0 : hlD1;
#pragma unroll
      for (int mt = 0; mt < 4; ++mt)
#pragma unroll
        for (int bt = 0; bt < 4; ++bt) {
          int u = 16 * jz + 4 * mt + quad;
          int bl = 16 * bt + l15;
          float v0 = acc[mt][bt][0] + biasv[mt][0];
          float v1 = acc[mt][bt][1] + biasv[mt][1];
          float v2 = acc[mt][bt][2] + biasv[mt][2];
          float v3 = acc[mt][bt][3] + biasv[mt][3];
          float m = fmaxf(fmaxf(v0, v1), fmaxf(v2, v3));
          float e0 = __expf(v0 - m), e1 = __expf(v1 - m);
          float e2 = __expf(v2 - m), e3 = __expf(v3 - m);
          float inv = 1.f / (e0 + e1 + e2 + e3);
          float hl = hlF[bl * HPITCH + u];
          float ht = htopF[bl * HPITCH + u];
          float hd = hdF[bl * HPITCH + u];
          hz_r[mt][bt] = (e1 * hl + e2 * ht + e3 * hd) * inv;  // zl,zt,zd fold
          zi_r[mt][bt] = e0 * inv;
        }
    }
    __syncthreads();                                             // B4

    // ---- GEMM2 (z-waves only): hU+cw over K=416 incl. Wij block ----
    f32x4 acc2[4];
    if (wave >= 6 && wave < 14) {
#pragma unroll
      for (int bt = 0; bt < 4; ++bt) acc2[bt] = (f32x4){0.f, 0.f, 0.f, 0.f};
#pragma unroll
      for (int kb = 0; kb < 13; ++kb) {
        bf16x8 wf = *(const bf16x8*)(wp2 + ((size_t)(kb * 8 + jz) * 64 + lane) * 8);
#pragma unroll
        for (int bt = 0; bt < 4; ++bt) {
          bf16x8 qf = *(const bf16x8*)(lds + (size_t)(bt * 16 + l15) * QPITCH + kb * 32 + quad * 8);
          acc2[bt] = __builtin_amdgcn_mfma_f32_16x16x32_bf16(wf, qf, acc2[bt], 0, 0, 0);
        }
      }
    }
    __syncthreads();                                             // B5

    // ---- combine (z-waves, in-register) ∥ stage-A (all threads) ----
    if (wave >= 6 && wave < 14) {
      // acc2[bt][g] holds u = 16*jz + 4*g + quad (row-permuted wp2) -> g==mt
#pragma unroll
      for (int mt = 0; mt < 4; ++mt)
#pragma unroll
        for (int bt = 0; bt < 4; ++bt) {
          float h = hz_r[mt][bt] + zi_r[mt][bt] * tanh_fast(acc2[bt][mt] + bij_r[mt]);
          int bl = 16 * bt + l15;
          int uu = 16 * jz + 4 * mt + quad;
          htopF[bl * HPITCH + uu] = h;                 // fp32 ht for l+1 + relay src
          lds[(size_t)bl * QPITCH + uu] = f2bf(h);     // bf16 ht col for l+1
        }
    }
    if (l < 79) {
      // hd (q cols 256..383) <- hl fp32 of this step; x col from prefetch
      const float* hdF = ((l + 1) & 1) ? hlD0 : hlD1;
      int idx = tid * 8, bl = idx >> 7, u = idx & 127;
      f32x4 a = *(const f32x4*)(hdF + bl * HPITCH + u);
      f32x4 b = *(const f32x4*)(hdF + bl * HPITCH + u + 4);
      *(ushort4v*)(lds + (size_t)bl * QPITCH + 256 + u)     = (ushort4v){f2bf(a[0]), f2bf(a[1]), f2bf(a[2]), f2bf(a[3])};
      *(ushort4v*)(lds + (size_t)bl * QPITCH + 256 + u + 4) = (ushort4v){f2bf(b[0]), f2bf(b[1]), f2bf(b[2]), f2bf(b[3])};
      *(ushort2v*)(lds + (size_t)bb * QPITCH + 384 + cc) = __builtin_bit_cast(ushort2v, xn);
    }
    __syncthreads();                                             // B6

    // ---- relay publish: coalesced device-scope stores of h(l) ----
    {
      int idx = tid * 8, bl = idx >> 7, u = idx & 127;
      f32x4 a = *(const f32x4*)(htopF + bl * HPITCH + u);
      f32x4 b = *(const f32x4*)(htopF + bl * HPITCH + u + 4);
      float* dst = ringMine + (size_t)(l % 3) * 8192 + idx;
      llc_store16(dst, a);
      llc_store16(dst + 4, b);
      if (isOut && l == 79) {
        *(f32x4*)(out + (size_t)(bh * 8192) + idx)     = a;
        *(f32x4*)(out + (size_t)(bh * 8192) + idx + 4) = b;
      }
      asm volatile("s_waitcnt vmcnt(0)" ::: "memory");
    }
    __syncthreads();                                             // B7 (stores drained)
    if (tid == 0)
      __hip_atomic_store(&g_progress[blk], l + 1, __ATOMIC_RELAXED, __HIP_MEMORY_SCOPE_AGENT);
  }
}

// ---------------------------------------------------------------------------
extern "C" void kernel_launch(void* const* d_in, const int* in_sizes, int n_in,
                              void* d_out, int out_size, void* d_ws, size_t ws_size,
                              hipStream_t stream) {
  const float* x   = (const float*)d_in[0];
  const float* Wr  = (const float*)d_in[1];
  const float* br  = (const float*)d_in[2];
  const float* Wz  = (const float*)d_in[3];
  const float* bz  = (const float*)d_in[4];
  const float* Wij = (const float*)d_in[5];
  const float* bij = (const float*)d_in[6];
  const float* WU  = (const float*)d_in[7];
  float* out = (float*)d_out;

  // ws layout: wp1 | wp2 | bfused | ring | xp
  char* ws = (char*)d_ws;
  unsigned short* wp1 = (unsigned short*)(ws);                 //    745,472 B
  unsigned short* wp2 = (unsigned short*)(ws + 745472);        //    106,496 B
  float* bfused       = (float*)(ws + 851968);                 //      4,096 B
  float* ring         = (float*)(ws + 856064);                 // 15,728,640 B
  // xp: 160 blocks x 80 l x 2048 bf16 = 52,428,800 B (only if ws allows)
  unsigned short* xp  = (ws_size >= 69013504ull)
                        ? (unsigned short*)(ws + 16584704) : nullptr;

  (void)hipFuncSetAttribute((const void*)gru_persist,
                            hipFuncAttributeMaxDynamicSharedMemorySize, 155648);

  prep_kernel<<<834, 64, 0, stream>>>(Wr, Wz, Wij, WU, br, bz, bij, wp1, wp2, bfused);
  gru_persist<<<160, 1024, 155648, stream>>>(x, bfused, wp1, wp2, ring, xp, out);
}

// Round 10
// 4921.657 us; speedup vs baseline: 2.0875x; 1.5392x over previous
//
#include <hip/hip_runtime.h>
#include <stdint.h>

// SpatialGRU on MI355X, round 12: improved cell in the multi-launch frame.
// r11 post-mortem: warm-touch regressed (+22%); persistent best r9=6213us is
// WORSE than the 5897us multi-launch baseline. Recurrence analysis: the 38us
// slot is the post-sync tail; the device-side protocol (sc1 write-through,
// vmcnt fences, spin, 7 barriers) costs more than kernel relaunch, which
// gives coherence free at the dispatch boundary (plain cached ring, 4
// barriers). So: 159 diag launches + the cell improvements proven in r6-r9:
//  - Wij folded into z-wave GEMM2 (K=13, row-permuted wp2), in-register
//    combine, ZERO global scratch (r0 cell burned 96KB RW/step + wij waves);
//  - single 13-kb GEMM1 (no A/B split -- nothing to hide);
//  - x via one-time xp transpose: 4KB contiguous nt read/step (r0 cell read
//    256KB of strided HBM lines per step -- its biggest hidden cost);
//  - fp32 h staging in LDS for the z-fold; coalesced relay publish, plain
//    write-back stores. No spin protocol -> no deadlock class.

typedef __bf16 bf16x8 __attribute__((ext_vector_type(8)));
typedef float  f32x4  __attribute__((ext_vector_type(4)));
typedef unsigned short ushort4v __attribute__((ext_vector_type(4)));
typedef unsigned short ushort2v __attribute__((ext_vector_type(2)));

#define QPITCH 424   // 416 q cols + 8 pad (bf16 elems)
#define HPITCH 132   // fp32 h rows padded +4

__device__ __forceinline__ unsigned short f2bf(float x) {
  unsigned int u = __builtin_bit_cast(unsigned int, x);
  u = u + 0x7FFFu + ((u >> 16) & 1u);          // round-to-nearest-even
  return (unsigned short)(u >> 16);
}
__device__ __forceinline__ float bf2f(unsigned short h) {
  unsigned int u = ((unsigned int)h) << 16;
  return __builtin_bit_cast(float, u);
}
__device__ __forceinline__ float sigm(float x) {
  x = fminf(fmaxf(x, -30.f), 30.f);
  return 1.f / (1.f + __expf(-x));
}
__device__ __forceinline__ float tanh_fast(float x) {
  x = fminf(fmaxf(x, -15.f), 15.f);
  float e = __expf(2.f * x);
  return (e - 1.f) / (e + 1.f);
}

// ---------------------------------------------------------------------------
// prep: wp1 = fused [Wr | Wz] (896 x 416) in MFMA A-frag order;
//       wp2 = [WU' | Wij] (128 x 416), rows permuted within each 16-tile
//       (WU row 4(f&3)+(f>>2) at frag slot f) so GEMM2 output lanes align
//       with GEMM1's z-lane (u,bl) mapping; bfused. (r9-verified numerics.)
// ---------------------------------------------------------------------------
__global__ void prep_kernel(const float* __restrict__ Wr, const float* __restrict__ Wz,
                            const float* __restrict__ Wij, const float* __restrict__ WU,
                            const float* __restrict__ br, const float* __restrict__ bz,
                            const float* __restrict__ bij,
                            unsigned short* __restrict__ wp1, unsigned short* __restrict__ wp2,
                            float* __restrict__ bfused) {
  int blk = blockIdx.x, lane = threadIdx.x;
  if (blk < 728) {                       // 13 kb * 56 ntiles for W' (n<896)
    int kb = blk / 56, nt = blk % 56;
    int n = nt * 16 + (lane & 15);
    int kb8 = kb * 32 + (lane >> 4) * 8;
    unsigned short v[8];
#pragma unroll
    for (int j = 0; j < 8; ++j) {
      int k = kb8 + j; float w;
      if (n < 384) w = Wr[n * 416 + k];
      else { int u = (n - 384) >> 2, g = (n - 384) & 3; w = Wz[(g * 128 + u) * 416 + k]; }
      v[j] = f2bf(w);
    }
    ushort4v* dst = (ushort4v*)(wp1 + ((size_t)(kb * 56 + nt) * 64 + lane) * 8);
    dst[0] = (ushort4v){v[0], v[1], v[2], v[3]};
    dst[1] = (ushort4v){v[4], v[5], v[6], v[7]};
  } else if (blk < 728 + 104) {          // 13 kb * 8 ntiles for [WU' | Wij]
    int b2 = blk - 728;
    int kb = b2 >> 3, nt = b2 & 7;
    int f = lane & 15;
    int u = nt * 16 + ((f & 3) * 4) + (f >> 2);   // row permutation
    int kb8 = kb * 32 + (lane >> 4) * 8;
    unsigned short v[8];
#pragma unroll
    for (int j = 0; j < 8; ++j) {
      int c = kb8 + j; float w;
      if (c < 384) {
        int s = (c < 128) ? c + 128 : (c < 256 ? c - 128 : c);  // hl,ht,hd -> ht,hl,hd
        w = WU[u * 384 + s];
      } else {
        w = Wij[u * 32 + (c - 384)];
      }
      v[j] = f2bf(w);
    }
    ushort4v* dst = (ushort4v*)(wp2 + ((size_t)(kb * 8 + nt) * 64 + lane) * 8);
    dst[0] = (ushort4v){v[0], v[1], v[2], v[3]};
    dst[1] = (ushort4v){v[4], v[5], v[6], v[7]};
  } else {                               // fused bias (1024 fp32)
#pragma unroll
    for (int i = 0; i < 16; ++i) {
      int n = lane * 16 + i; float v;
      if (n < 384) v = br[n];
      else if (n < 896) { int u = (n - 384) >> 2, g = (n - 384) & 3; v = bz[g * 128 + u]; }
      else v = bij[n - 896];
      bfused[n] = v;
    }
  }
}

// ---------------------------------------------------------------------------
// prep2: per (rc,bh) column transpose of x into contiguous bf16 xp[80][2048].
// Cached gathers (32 rc-blocks share each 128B line -> LLC/L2 dedup, r9-
// verified); nt stores (write-once, no L2 pollution).
// ---------------------------------------------------------------------------
__global__ __launch_bounds__(1024)
void prep2_kernel(const float* __restrict__ x, unsigned short* __restrict__ xp) {
  const int blk = blockIdx.x;
  const int rc = (blk < 80) ? blk : blk - 80;
  const int bh = (blk < 80) ? 0 : 1;
  const int i2 = threadIdx.x * 2;
  const float* xb = x + (size_t)(bh * 2048 + i2) * 6400 + rc;
  unsigned short* xpB = xp + (size_t)blk * 163840;
#pragma unroll 4
  for (int l = 0; l < 80; ++l) {
    float v0 = xb[l * 80];
    float v1 = xb[6400 + l * 80];
    ushort2v o = (ushort2v){f2bf(v0), f2bf(v1)};
    __builtin_nontemporal_store(__builtin_bit_cast(unsigned int, o),
                                (unsigned int*)(xpB + (size_t)l * 2048 + i2));
  }
}

// one GEMM1 K-step (16 MFMA over the wave's 64n x 64b tile)
#define G1_STEP(KB)                                                                        \
  {                                                                                        \
    bf16x8 wf[4], qf[4];                                                                   \
    _Pragma("unroll")                                                                      \
    for (int mt = 0; mt < 4; ++mt)                                                         \
      wf[mt] = *(const bf16x8*)(wp1 + ((size_t)((KB) * 56 + ntb + mt) * 64 + lane) * 8);   \
    _Pragma("unroll")                                                                      \
    for (int bt = 0; bt < 4; ++bt)                                                         \
      qf[bt] = *(const bf16x8*)(lds + (size_t)(bt * 16 + l15) * QPITCH + (KB) * 32 + quad * 8); \
    _Pragma("unroll")                                                                      \
    for (int mt = 0; mt < 4; ++mt)                                                         \
      _Pragma("unroll")                                                                    \
      for (int bt = 0; bt < 4; ++bt)                                                       \
        acc[mt][bt] = __builtin_amdgcn_mfma_f32_16x16x32_bf16(wf[mt], qf[bt], acc[mt][bt], 0, 0, 0); \
  }

// ---------------------------------------------------------------------------
// One (cell, batch-half) per block per dispatch. LDS (155,648 B):
//   q bf16 [64][QPITCH]     @ 0       cols: ht|hl|hd|x
//   htopF fp32 [64][HPITCH] @ 54,272  (fold input; combine output; relay src)
//   hlF   fp32 [64][HPITCH] @ 88,064
//   hdF   fp32 [64][HPITCH] @ 121,856
// Ring: 3 diag slots x 80 rc x 16384 fp32; dispatch boundary = sync.
// ---------------------------------------------------------------------------
__global__ __launch_bounds__(1024)
void diag_kernel(int d, const float* __restrict__ x, const float* __restrict__ bfused,
                 const unsigned short* __restrict__ wp1, const unsigned short* __restrict__ wp2,
                 float* __restrict__ ring,
                 const unsigned short* __restrict__ xp,  // nullable
                 float* __restrict__ out) {
  const int blk = blockIdx.x;
  const int rc = (blk < 80) ? blk : blk - 80;
  const int bh = (blk < 80) ? 0 : 1;
  const int l = d - rc;
  if (l < 0 || l >= 80) return;
  const int tid = threadIdx.x;
  const int wave = tid >> 6, lane = tid & 63;
  const int quad = lane >> 4, l15 = lane & 15;
  const int i2 = tid * 2;
  const int bb = i2 >> 5, cc = i2 & 31;

  extern __shared__ char smem[];
  unsigned short* lds = (unsigned short*)smem;
  float* htopF = (float*)(smem + 54272);
  float* hlF   = (float*)(smem + 88064);
  float* hdF   = (float*)(smem + 121856);

  const bool vt = (l >= 1), vlft = (rc >= 1), vdg = vt && vlft;
  const float* slot1 = ring + (size_t)(((d + 2) % 3) * 80) * 16384;  // diag d-1
  const float* slot2 = ring + (size_t)(((d + 1) % 3) * 80) * 16384;  // diag d-2

  // ---- stage: 3 h-buffers (fp32 LDS + bf16 q cols) + x ----
  {
    const int off = tid * 8, bl = off >> 7, u = off & 127;
    const float* srcs[3] = {
      slot1 + (size_t)rc * 16384 + bh * 8192,         // ht
      slot1 + (size_t)(rc - 1) * 16384 + bh * 8192,   // hl
      slot2 + (size_t)(rc - 1) * 16384 + bh * 8192 }; // hd
    const bool val[3] = {vt, vlft, vdg};
    float* bufs[3] = {htopF, hlF, hdF};
#pragma unroll
    for (int bI = 0; bI < 3; ++bI) {
      f32x4 a = (f32x4){0.f, 0.f, 0.f, 0.f}, b = a;
      if (val[bI]) {
        a = *(const f32x4*)(srcs[bI] + off);
        b = *(const f32x4*)(srcs[bI] + off + 4);
      }
      *(f32x4*)(bufs[bI] + bl * HPITCH + u)     = a;
      *(f32x4*)(bufs[bI] + bl * HPITCH + u + 4) = b;
      *(ushort4v*)(lds + (size_t)bl * QPITCH + bI * 128 + u) =
          (ushort4v){f2bf(a[0]), f2bf(a[1]), f2bf(a[2]), f2bf(a[3])};
      *(ushort4v*)(lds + (size_t)bl * QPITCH + bI * 128 + u + 4) =
          (ushort4v){f2bf(b[0]), f2bf(b[1]), f2bf(b[2]), f2bf(b[3])};
    }
    if (xp) {
      unsigned int t = __builtin_nontemporal_load(
          (const unsigned int*)(xp + (size_t)blk * 163840 + (size_t)l * 2048 + i2));
      *(ushort2v*)(lds + (size_t)bb * QPITCH + 384 + cc) = __builtin_bit_cast(ushort2v, t);
    } else {
      const float* xb = x + (size_t)l * 80 + rc;
      float v0 = xb[(size_t)(bh * 2048 + i2) * 6400];
      float v1 = xb[(size_t)(bh * 2048 + i2 + 1) * 6400];
      *(ushort2v*)(lds + (size_t)bb * QPITCH + 384 + cc) = (ushort2v){f2bf(v0), f2bf(v1)};
    }
  }
  __syncthreads();                                             // B1

  const int ntb = wave * 4;
  const int jz = wave - 6;

  f32x4 biasv[4];
#pragma unroll
  for (int mt = 0; mt < 4; ++mt)
    biasv[mt] = *(const f32x4*)(bfused + ((wave < 14 ? wave : 0) * 64) + mt * 16 + quad * 4);
  float bij_r[4];
#pragma unroll
  for (int mt = 0; mt < 4; ++mt)
    bij_r[mt] = (wave >= 6 && wave < 14) ? bfused[896 + 16 * jz + 4 * mt + quad] : 0.f;

  // ---- GEMM1: all 13 kb (waves 0..13) ----
  f32x4 acc[4][4];
  if (wave < 14) {
#pragma unroll
    for (int mt = 0; mt < 4; ++mt)
#pragma unroll
      for (int bt = 0; bt < 4; ++bt) acc[mt][bt] = (f32x4){0.f, 0.f, 0.f, 0.f};
#pragma unroll
    for (int kb = 0; kb < 13; ++kb) { G1_STEP(kb) }
  }
  __syncthreads();                                             // B2

  // ---- elementwise ----
  float hz_r[4][4], zi_r[4][4];
  if (wave < 6) {
    // r class: sigmoid, A2' = r*q in place (shift maps r col -> q col)
    const int rn0 = wave * 64;
    const int shift = (rn0 < 128) ? 128 : (rn0 < 256 ? -128 : 0);
#pragma unroll
    for (int mt = 0; mt < 4; ++mt)
#pragma unroll
      for (int bt = 0; bt < 4; ++bt) {
        int n0 = rn0 + mt * 16 + quad * 4;
        int row = bt * 16 + l15;
        unsigned short* p = lds + (size_t)row * QPITCH + n0 + shift;
        ushort4v qv = *(ushort4v*)p;
        ushort4v o;
#pragma unroll
        for (int g = 0; g < 4; ++g) {
          float r = sigm(acc[mt][bt][g] + biasv[mt][g]);
          o[g] = f2bf(bf2f(qv[g]) * r);
        }
        *(ushort4v*)p = o;
      }
  } else if (wave < 14) {
    // z class: lane-local softmax; fold fp32 h's; keep hz/zi in registers
#pragma unroll
    for (int mt = 0; mt < 4; ++mt)
#pragma unroll
      for (int bt = 0; bt < 4; ++bt) {
        int u = 16 * jz + 4 * mt + quad;
        int bl = 16 * bt + l15;
        float v0 = acc[mt][bt][0] + biasv[mt][0];
        float v1 = acc[mt][bt][1] + biasv[mt][1];
        float v2 = acc[mt][bt][2] + biasv[mt][2];
        float v3 = acc[mt][bt][3] + biasv[mt][3];
        float m = fmaxf(fmaxf(v0, v1), fmaxf(v2, v3));
        float e0 = __expf(v0 - m), e1 = __expf(v1 - m);
        float e2 = __expf(v2 - m), e3 = __expf(v3 - m);
        float inv = 1.f / (e0 + e1 + e2 + e3);
        float hl = hlF[bl * HPITCH + u];
        float ht = htopF[bl * HPITCH + u];
        float hd = hdF[bl * HPITCH + u];
        hz_r[mt][bt] = (e1 * hl + e2 * ht + e3 * hd) * inv;  // zl,zt,zd fold
        zi_r[mt][bt] = e0 * inv;
      }
  }
  __syncthreads();                                             // B3

  // ---- GEMM2 (z-waves): hU+cw over K=416 incl. Wij block; combine ----
  if (wave >= 6 && wave < 14) {
    f32x4 acc2[4];
#pragma unroll
    for (int bt = 0; bt < 4; ++bt) acc2[bt] = (f32x4){0.f, 0.f, 0.f, 0.f};
#pragma unroll
    for (int kb = 0; kb < 13; ++kb) {
      bf16x8 wf = *(const bf16x8*)(wp2 + ((size_t)(kb * 8 + jz) * 64 + lane) * 8);
#pragma unroll
      for (int bt = 0; bt < 4; ++bt) {
        bf16x8 qf = *(const bf16x8*)(lds + (size_t)(bt * 16 + l15) * QPITCH + kb * 32 + quad * 8);
        acc2[bt] = __builtin_amdgcn_mfma_f32_16x16x32_bf16(wf, qf, acc2[bt], 0, 0, 0);
      }
    }
    // acc2[bt][g] holds u = 16*jz + 4*g + quad (row-permuted wp2) -> g==mt
#pragma unroll
    for (int mt = 0; mt < 4; ++mt)
#pragma unroll
      for (int bt = 0; bt < 4; ++bt) {
        float h = hz_r[mt][bt] + zi_r[mt][bt] * tanh_fast(acc2[bt][mt] + bij_r[mt]);
        int bl = 16 * bt + l15;
        int uu = 16 * jz + 4 * mt + quad;
        htopF[bl * HPITCH + uu] = h;                 // relay source
      }
  }
  __syncthreads();                                             // B4

  // ---- relay publish: coalesced plain stores (write-back L2; dispatch
  //      boundary provides cross-XCD visibility) ----
  {
    const int idx = tid * 8, bl = idx >> 7, u = idx & 127;
    f32x4 a = *(const f32x4*)(htopF + bl * HPITCH + u);
    f32x4 b = *(const f32x4*)(htopF + bl * HPITCH + u + 4);
    float* dst = ring + (size_t)((d % 3) * 80 + rc) * 16384 + bh * 8192 + idx;
    *(f32x4*)(dst)     = a;
    *(f32x4*)(dst + 4) = b;
    if (d == 158) {                                  // only rc==79 blocks run
      *(f32x4*)(out + (size_t)(bh * 8192) + idx)     = a;
      *(f32x4*)(out + (size_t)(bh * 8192) + idx + 4) = b;
    }
  }
}

// ---------------------------------------------------------------------------
extern "C" void kernel_launch(void* const* d_in, const int* in_sizes, int n_in,
                              void* d_out, int out_size, void* d_ws, size_t ws_size,
                              hipStream_t stream) {
  const float* x   = (const float*)d_in[0];
  const float* Wr  = (const float*)d_in[1];
  const float* br  = (const float*)d_in[2];
  const float* Wz  = (const float*)d_in[3];
  const float* bz  = (const float*)d_in[4];
  const float* Wij = (const float*)d_in[5];
  const float* bij = (const float*)d_in[6];
  const float* WU  = (const float*)d_in[7];
  float* out = (float*)d_out;

  // ws layout: wp1 | wp2 | bfused | ring | xp
  char* ws = (char*)d_ws;
  unsigned short* wp1 = (unsigned short*)(ws);                 //    745,472 B
  unsigned short* wp2 = (unsigned short*)(ws + 745472);        //    106,496 B
  float* bfused       = (float*)(ws + 851968);                 //      4,096 B
  float* ring         = (float*)(ws + 856064);                 // 15,728,640 B
  // xp: 160 blocks x 80 l x 2048 bf16 = 52,428,800 B (only if ws allows)
  unsigned short* xp  = (ws_size >= 69013504ull)
                        ? (unsigned short*)(ws + 16584704) : nullptr;

  (void)hipFuncSetAttribute((const void*)diag_kernel,
                            hipFuncAttributeMaxDynamicSharedMemorySize, 155648);

  prep_kernel<<<833, 64, 0, stream>>>(Wr, Wz, Wij, WU, br, bz, bij, wp1, wp2, bfused);
  if (xp) prep2_kernel<<<160, 1024, 0, stream>>>(x, xp);
  for (int d = 0; d < 159; ++d)
    diag_kernel<<<160, 1024, 155648, stream>>>(d, x, bfused, wp1, wp2, ring, xp, out);
}